// Round 1
// baseline (186.894 us; speedup 1.0000x reference)
//
#include <hip/hip_runtime.h>

typedef _Float16 f16x8 __attribute__((ext_vector_type(8)));
typedef _Float16 f16x4 __attribute__((ext_vector_type(4)));
typedef float    f32x4 __attribute__((ext_vector_type(4)));

namespace {
constexpr int kN = 4, kL = 1024, kS = 1024, kH = 16, kE = 64, kD = 64;
constexpr int kKRow = kH * kE;   // float stride between consecutive s rows of K
constexpr int kVRow = kH * kD;   // float stride between consecutive s rows of V
}

__device__ __forceinline__ f16x8 load_cvt8(const float* __restrict__ p) {
  const float4 a = *reinterpret_cast<const float4*>(p);
  const float4 b = *reinterpret_cast<const float4*>(p + 4);
  f16x8 r;
  r[0] = (_Float16)a.x; r[1] = (_Float16)a.y;
  r[2] = (_Float16)a.z; r[3] = (_Float16)a.w;
  r[4] = (_Float16)b.x; r[5] = (_Float16)b.y;
  r[6] = (_Float16)b.z; r[7] = (_Float16)b.w;
  return r;
}

// One wave owns 16 query rows of one (n,h); iterates all S in 32-key tiles.
// Swapped layout: scores tile = S^T[s][q] = K(s,e) . Q^T(e,q) via
// mfma_f32_16x16x32_f16 (A=K frag, B=Q frag). C/D layout (col=lane&15=q,
// row=4*(lane>>4)+r=s) == B-frag layout of mfma_f32_16x16x16f16, so the
// softmaxed P^T feeds PV (O^T = V^T . P^T) directly from registers.
__global__ __launch_bounds__(256)
void attn_fwd_kernel(const float* __restrict__ Q, const float* __restrict__ K,
                     const float* __restrict__ V, const float* __restrict__ M,
                     const float* __restrict__ KLN, float* __restrict__ O)
{
  const int lane = threadIdx.x & 63;
  const int wave = threadIdx.x >> 6;
  const int qc   = lane & 15;   // query column in every C/D tile
  const int g    = lane >> 4;   // 16-lane group (0..3)

  const int qb = blockIdx.x & (kL/64 - 1);   // 16 q-blocks of 64
  const int nh = blockIdx.x / (kL/64);
  const int h  = nh % kH;
  const int n  = nh / kH;

  const int qrow = qb*64 + wave*16 + qc;     // this lane's query row

  const float* Qp = Q + ((size_t)((size_t)n*kL + qrow)*kH + h)*kE;
  const float* Kp = K + ((size_t)n*kS*kH + (size_t)h)*kE;
  const float* Vp = V + ((size_t)n*kS*kH + (size_t)h)*kD;
  const float* Mp = M + (size_t)qrow*kS;
  const float* Lp = KLN + (size_t)n*kS;

  // Q B-fragments (hoisted): B[k=e][col=q], lane holds e = ec*32 + 8g + j
  const f16x8 qf0 = load_cvt8(Qp + 8*g);
  const f16x8 qf1 = load_cvt8(Qp + 32 + 8*g);

  const f32x4 zero4 = {0.f, 0.f, 0.f, 0.f};
  f32x4 acc[4];   // O^T d-tiles: acc[t][r] = O^T[16t + 4g + r][qc]
  #pragma unroll
  for (int t = 0; t < 4; ++t) acc[t] = zero4;

  float m = -1e30f, lsum = 0.f;
  constexpr float SCL = 0.125f * 1.44269504088896340736f;  // temp * log2(e)

  for (int s0 = 0; s0 < kS; s0 += 32) {
    // ---- QK^T: two 16-key subtiles, E=64 in two K=32 chunks ----
    f32x4 sc[2];
    #pragma unroll
    for (int st = 0; st < 2; ++st) {
      const float* kr = Kp + (size_t)(s0 + st*16 + qc) * kKRow;  // A row = s
      const f16x8 kf0 = load_cvt8(kr + 8*g);
      const f16x8 kf1 = load_cvt8(kr + 32 + 8*g);
      f32x4 c = zero4;
      c = __builtin_amdgcn_mfma_f32_16x16x32_f16(kf0, qf0, c, 0, 0, 0);
      c = __builtin_amdgcn_mfma_f32_16x16x32_f16(kf1, qf1, c, 0, 0, 0);
      sc[st] = c;
    }

    // ---- logits in log2 domain: x = (qk + mask + klen) * temp*log2e ----
    float x[8];
    #pragma unroll
    for (int st = 0; st < 2; ++st) {
      #pragma unroll
      for (int r = 0; r < 4; ++r) {
        const int s = s0 + st*16 + 4*g + r;
        x[st*4 + r] = (sc[st][r] + Mp[s] + Lp[s]) * SCL;
      }
    }

    // ---- online softmax: reduce over 8 in-lane + lanes {qc,+16,+32,+48} ----
    float tmax = x[0];
    #pragma unroll
    for (int i = 1; i < 8; ++i) tmax = fmaxf(tmax, x[i]);
    tmax = fmaxf(tmax, __shfl_xor(tmax, 16));
    tmax = fmaxf(tmax, __shfl_xor(tmax, 32));

    const float mnew = fmaxf(m, tmax);
    const float resc = __builtin_amdgcn_exp2f(m - mnew);
    m = mnew;

    float p[8];
    float ts = 0.f;
    #pragma unroll
    for (int i = 0; i < 8; ++i) {
      p[i] = __builtin_amdgcn_exp2f(x[i] - mnew);
      ts += p[i];
    }
    ts += __shfl_xor(ts, 16);
    ts += __shfl_xor(ts, 32);
    lsum = lsum * resc + ts;
    #pragma unroll
    for (int t = 0; t < 4; ++t) acc[t] *= resc;

    // ---- PV: O^T[d][q] += V^T(d,s) . P^T(s,q), K=16 per subtile ----
    #pragma unroll
    for (int st = 0; st < 2; ++st) {
      f16x4 pb;  // B-frag: k = 4g+j == C/D row layout of sc[st]
      pb[0] = (_Float16)p[st*4 + 0];
      pb[1] = (_Float16)p[st*4 + 1];
      pb[2] = (_Float16)p[st*4 + 2];
      pb[3] = (_Float16)p[st*4 + 3];
      const float* vb = Vp + (size_t)(s0 + st*16 + 4*g) * kVRow + qc;
      #pragma unroll
      for (int t = 0; t < 4; ++t) {
        f16x4 vf;  // A-frag: A[d = qc within tile][k = s = 4g+j]
        vf[0] = (_Float16)vb[t*16 + 0*kVRow];
        vf[1] = (_Float16)vb[t*16 + 1*kVRow];
        vf[2] = (_Float16)vb[t*16 + 2*kVRow];
        vf[3] = (_Float16)vb[t*16 + 3*kVRow];
        acc[t] = __builtin_amdgcn_mfma_f32_16x16x16f16(vf, pb, acc[t], 0, 0, 0);
      }
    }
  }

  // ---- epilogue: normalize and write O[n][qrow][h][d] ----
  const float inv = 1.f / lsum;
  float* Op = O + ((size_t)((size_t)n*kL + qrow)*kH + h)*kD;
  #pragma unroll
  for (int t = 0; t < 4; ++t) {
    #pragma unroll
    for (int r = 0; r < 4; ++r) {
      Op[t*16 + 4*g + r] = acc[t][r] * inv;
    }
  }
}

extern "C" void kernel_launch(void* const* d_in, const int* in_sizes, int n_in,
                              void* d_out, int out_size, void* d_ws, size_t ws_size,
                              hipStream_t stream) {
  const float* Q   = (const float*)d_in[0];
  const float* K   = (const float*)d_in[1];
  const float* V   = (const float*)d_in[2];
  const float* M   = (const float*)d_in[3];
  const float* KLN = (const float*)d_in[4];
  float* O = (float*)d_out;

  dim3 grid(kN * kH * (kL / 64));   // 1024 blocks
  dim3 block(256);                  // 4 independent waves, 16 queries each
  attn_fwd_kernel<<<grid, block, 0, stream>>>(Q, K, V, M, KLN, O);
}

// Round 2
// 84.041 us; speedup vs baseline: 2.2238x; 2.2238x over previous
//
#include <hip/hip_runtime.h>

typedef _Float16 f16x8 __attribute__((ext_vector_type(8)));
typedef _Float16 f16x4 __attribute__((ext_vector_type(4)));
typedef float    f32x4 __attribute__((ext_vector_type(4)));

namespace {
constexpr int kN = 4, kL = 1024, kS = 1024, kH = 16, kE = 64, kD = 64;
constexpr int kRow = kH * kE;   // 1024 floats: s-row stride of K and V
constexpr int KVB  = 64;        // keys per LDS chunk
constexpr int NCH  = kS / KVB;  // 16 chunks
constexpr int LDK  = 72;        // padded f16 row stride in LDS (64 + 8)
}

// One block = 4 waves = 64 queries of one (n,h). K/V chunks staged in LDS
// (f16, V transposed), double-buffered, shared across the 4 waves.
// Swapped scores: S^T[s][q] = K.Q^T via mfma_16x16x32_f16 (A=K, B=Q);
// C/D layout (col=lane&15=q, row=4g+r=s) == B-frag layout of 16x16x16 f16,
// so softmaxed P^T feeds PV (O^T = V^T.P^T) directly from registers.
__global__ __launch_bounds__(256, 4)
void attn_fwd_kernel(const float* __restrict__ Q, const float* __restrict__ K,
                     const float* __restrict__ V, const float* __restrict__ M,
                     const float* __restrict__ KLN, float* __restrict__ O)
{
  __shared__ _Float16 Ks[2][KVB][LDK];   // [buf][s][e]
  __shared__ _Float16 Vt[2][kD][LDK];    // [buf][d][s]  (transposed)

  const int tid  = threadIdx.x;
  const int lane = tid & 63;
  const int wave = tid >> 6;
  const int qc   = lane & 15;   // query column in every C/D tile
  const int g    = lane >> 4;   // 16-lane group (0..3)
  const int sr   = tid >> 4;    // staging: row within a 16-row slab
  const int sc4  = tid & 15;    // staging: float4 column

  const int qb = blockIdx.x & (kL/64 - 1);
  const int nh = blockIdx.x / (kL/64);
  const int h  = nh % kH;
  const int n  = nh / kH;
  const int qrow = qb*64 + wave*16 + qc;

  const float* Qp = Q + ((size_t)((size_t)n*kL + qrow)*kH + h)*kE;
  const float* Kp = K + ((size_t)n*kS*kH + (size_t)h)*kE;
  const float* Vp = V + ((size_t)n*kS*kH + (size_t)h)*kD;
  const float* Mp = M + (size_t)qrow*kS;
  const float* Lp = KLN + (size_t)n*kS;

  // Q B-fragments (hoisted): B[k=e][col=q], lane holds e = 32*ec + 8g + j
  f16x8 qf0, qf1;
  {
    const float4 a = *reinterpret_cast<const float4*>(Qp + 8*g);
    const float4 b = *reinterpret_cast<const float4*>(Qp + 8*g + 4);
    const float4 cda = *reinterpret_cast<const float4*>(Qp + 32 + 8*g);
    const float4 cdb = *reinterpret_cast<const float4*>(Qp + 32 + 8*g + 4);
    qf0[0]=(_Float16)a.x; qf0[1]=(_Float16)a.y; qf0[2]=(_Float16)a.z; qf0[3]=(_Float16)a.w;
    qf0[4]=(_Float16)b.x; qf0[5]=(_Float16)b.y; qf0[6]=(_Float16)b.z; qf0[7]=(_Float16)b.w;
    qf1[0]=(_Float16)cda.x; qf1[1]=(_Float16)cda.y; qf1[2]=(_Float16)cda.z; qf1[3]=(_Float16)cda.w;
    qf1[4]=(_Float16)cdb.x; qf1[5]=(_Float16)cdb.y; qf1[6]=(_Float16)cdb.z; qf1[7]=(_Float16)cdb.w;
  }

  const f32x4 zero4 = {0.f, 0.f, 0.f, 0.f};
  f32x4 acc[4];
  #pragma unroll
  for (int t = 0; t < 4; ++t) acc[t] = zero4;

  float m = -1e30f, lsum = 0.f;
  constexpr float SCL = 0.125f * 1.44269504088896340736f;  // temp * log2(e)

  // ---- prologue: stage chunk 0 into buffer 0 ----
  #pragma unroll
  for (int i = 0; i < 4; ++i) {
    const int s = i*16 + sr;
    const float4 kv = *reinterpret_cast<const float4*>(Kp + (size_t)s*kRow + sc4*4);
    const float4 vv = *reinterpret_cast<const float4*>(Vp + (size_t)s*kRow + sc4*4);
    f16x4 kw;
    kw[0]=(_Float16)kv.x; kw[1]=(_Float16)kv.y; kw[2]=(_Float16)kv.z; kw[3]=(_Float16)kv.w;
    *reinterpret_cast<f16x4*>(&Ks[0][s][sc4*4]) = kw;
    Vt[0][sc4*4+0][s] = (_Float16)vv.x;
    Vt[0][sc4*4+1][s] = (_Float16)vv.y;
    Vt[0][sc4*4+2][s] = (_Float16)vv.z;
    Vt[0][sc4*4+3][s] = (_Float16)vv.w;
  }
  __syncthreads();

  int cur = 0;
  for (int c = 0; c < NCH; ++c) {
    const int s0 = c * KVB;
    const bool pre = (c + 1 < NCH);

    // ---- issue next-chunk global loads early (latency hides under compute)
    float4 ka[4], va[4];
    if (pre) {
      const int s1 = s0 + KVB;
      #pragma unroll
      for (int i = 0; i < 4; ++i) {
        const int s = s1 + i*16 + sr;
        ka[i] = *reinterpret_cast<const float4*>(Kp + (size_t)s*kRow + sc4*4);
        va[i] = *reinterpret_cast<const float4*>(Vp + (size_t)s*kRow + sc4*4);
      }
    }

    // ---- QK^T on staged chunk: 4 16-key subtiles, E=64 in two K=32 halves
    float x[16];
    #pragma unroll
    for (int st = 0; st < 4; ++st) {
      const f16x8 kf0 = *reinterpret_cast<const f16x8*>(&Ks[cur][st*16+qc][8*g]);
      const f16x8 kf1 = *reinterpret_cast<const f16x8*>(&Ks[cur][st*16+qc][32+8*g]);
      f32x4 cc = zero4;
      cc = __builtin_amdgcn_mfma_f32_16x16x32_f16(kf0, qf0, cc, 0, 0, 0);
      cc = __builtin_amdgcn_mfma_f32_16x16x32_f16(kf1, qf1, cc, 0, 0, 0);
      const float4 mv = *reinterpret_cast<const float4*>(&Mp[s0 + st*16 + 4*g]);
      const float4 lv = *reinterpret_cast<const float4*>(&Lp[s0 + st*16 + 4*g]);
      x[st*4+0] = (cc[0] + mv.x + lv.x) * SCL;
      x[st*4+1] = (cc[1] + mv.y + lv.y) * SCL;
      x[st*4+2] = (cc[2] + mv.z + lv.z) * SCL;
      x[st*4+3] = (cc[3] + mv.w + lv.w) * SCL;
    }

    // ---- online softmax over 16 in-lane + lane groups {+16,+32} ----
    float tmax = x[0];
    #pragma unroll
    for (int i = 1; i < 16; ++i) tmax = fmaxf(tmax, x[i]);
    tmax = fmaxf(tmax, __shfl_xor(tmax, 16));
    tmax = fmaxf(tmax, __shfl_xor(tmax, 32));

    const float mnew = fmaxf(m, tmax);
    const float resc = __builtin_amdgcn_exp2f(m - mnew);
    m = mnew;

    float p[16];
    float ts = 0.f;
    #pragma unroll
    for (int i = 0; i < 16; ++i) {
      p[i] = __builtin_amdgcn_exp2f(x[i] - mnew);
      ts += p[i];
    }
    ts += __shfl_xor(ts, 16);
    ts += __shfl_xor(ts, 32);
    lsum = lsum * resc + ts;
    #pragma unroll
    for (int t = 0; t < 4; ++t) acc[t] *= resc;

    // ---- PV: O^T[d][q] += V^T(d,s) . P^T(s,q) from LDS-transposed V ----
    #pragma unroll
    for (int st = 0; st < 4; ++st) {
      f16x4 pb;
      pb[0] = (_Float16)p[st*4+0];
      pb[1] = (_Float16)p[st*4+1];
      pb[2] = (_Float16)p[st*4+2];
      pb[3] = (_Float16)p[st*4+3];
      #pragma unroll
      for (int t = 0; t < 4; ++t) {
        const f16x4 vf = *reinterpret_cast<const f16x4*>(&Vt[cur][16*t+qc][st*16+4*g]);
        acc[t] = __builtin_amdgcn_mfma_f32_16x16x16f16(vf, pb, acc[t], 0, 0, 0);
      }
    }

    // ---- write next chunk into the other buffer, single barrier ----
    if (pre) {
      #pragma unroll
      for (int i = 0; i < 4; ++i) {
        const int s = i*16 + sr;
        f16x4 kw;
        kw[0]=(_Float16)ka[i].x; kw[1]=(_Float16)ka[i].y;
        kw[2]=(_Float16)ka[i].z; kw[3]=(_Float16)ka[i].w;
        *reinterpret_cast<f16x4*>(&Ks[cur^1][s][sc4*4]) = kw;
        Vt[cur^1][sc4*4+0][s] = (_Float16)va[i].x;
        Vt[cur^1][sc4*4+1][s] = (_Float16)va[i].y;
        Vt[cur^1][sc4*4+2][s] = (_Float16)va[i].z;
        Vt[cur^1][sc4*4+3][s] = (_Float16)va[i].w;
      }
      __syncthreads();
      cur ^= 1;
    }
  }

  // ---- epilogue: normalize, vectorized store O[n][qrow][h][d] ----
  const float inv = 1.f / lsum;
  float* Op = O + ((size_t)((size_t)n*kL + qrow)*kH + h)*kD;
  #pragma unroll
  for (int t = 0; t < 4; ++t) {
    float4 o;
    o.x = acc[t][0] * inv;
    o.y = acc[t][1] * inv;
    o.z = acc[t][2] * inv;
    o.w = acc[t][3] * inv;
    *reinterpret_cast<float4*>(Op + t*16 + 4*g) = o;
  }
}

extern "C" void kernel_launch(void* const* d_in, const int* in_sizes, int n_in,
                              void* d_out, int out_size, void* d_ws, size_t ws_size,
                              hipStream_t stream) {
  const float* Q   = (const float*)d_in[0];
  const float* K   = (const float*)d_in[1];
  const float* V   = (const float*)d_in[2];
  const float* M   = (const float*)d_in[3];
  const float* KLN = (const float*)d_in[4];
  float* O = (float*)d_out;

  dim3 grid(kN * kH * (kL / 64));   // 1024 blocks
  dim3 block(256);                  // 4 waves, 16 queries each
  attn_fwd_kernel<<<grid, block, 0, stream>>>(Q, K, V, M, KLN, O);
}

// Round 3
// 65.616 us; speedup vs baseline: 2.8483x; 1.2808x over previous
//
#include <hip/hip_runtime.h>

typedef _Float16 f16x8 __attribute__((ext_vector_type(8)));
typedef _Float16 f16x4 __attribute__((ext_vector_type(4)));
typedef float    f32x4 __attribute__((ext_vector_type(4)));

namespace {
constexpr int kN = 4, kL = 1024, kS = 1024, kH = 16, kE = 64, kD = 64;
constexpr int kRowF = kH * kE;   // 1024 floats: s-row stride of K and V
constexpr int KVB  = 64;         // keys per LDS chunk
constexpr int NCH  = kS / KVB;   // 16 chunks
constexpr int LDK  = 72;         // K row pad (f16): b128 frag reads 2-way-free
constexpr int LDV  = 68;         // Vt row pad (f16): scatter writes 4-way, b64 reads ~min
constexpr float SCL = 0.125f * 1.44269504088896340736f;  // 1/sqrt(E) * log2(e)
}

// Block = 2 waves x 32 queries of one (n,h). K/V chunks in LDS (f16, V
// transposed), double-buffered. Swapped scores: S^T = K.Q^T via
// mfma_16x16x32_f16; C/D layout (col=lane&15=q, row=4g+r=s) == B-frag of
// 16x16x16 f16, so P^T feeds PV (O^T = V^T.P^T) straight from registers.
// K/V fragments are read from LDS ONCE and reused for both q-subtiles.
__global__ __launch_bounds__(128, 2)
void attn_fwd_kernel(const float* __restrict__ Q, const float* __restrict__ K,
                     const float* __restrict__ V, const float* __restrict__ M,
                     const float* __restrict__ KLN, float* __restrict__ O)
{
  __shared__ _Float16 Ks[2][KVB][LDK];   // [buf][s][e]
  __shared__ _Float16 Vt[2][kD][LDV];    // [buf][d][s]  (transposed)

  const int tid  = threadIdx.x;
  const int lane = tid & 63;
  const int wave = tid >> 6;    // 0..1
  const int qc   = lane & 15;
  const int g    = lane >> 4;
  const int sr   = tid >> 4;    // staging row-in-slab 0..7
  const int sc4  = tid & 15;    // staging float4 column

  // XCD-aware swizzle (1024 % 8 == 0 -> bijective): all 16 q-blocks of an
  // (n,h) land on one XCD so K/V stay L2-resident there.
  const int swz = ((blockIdx.x & 7) << 7) | (blockIdx.x >> 3);
  const int nh = swz >> 4, qb = swz & 15;
  const int h = nh & (kH - 1), n = nh >> 4;

  const int qbase = qb*64 + wave*32;

  const float* Kp = K + ((size_t)n*kS*kH + h)*kE;
  const float* Vp = V + ((size_t)n*kS*kH + h)*kD;
  const float* Lp = KLN + (size_t)n*kS;

  // Hoisted Q B-fragments for both 16-q subtiles, pre-scaled by SCL.
  f16x8 qf[2][2];
  int qrow[2];
  #pragma unroll
  for (int u = 0; u < 2; ++u) {
    qrow[u] = qbase + u*16 + qc;
    const float* Qp = Q + ((size_t)((size_t)n*kL + qrow[u])*kH + h)*kE;
    #pragma unroll
    for (int hf = 0; hf < 2; ++hf) {
      const float4 a = *reinterpret_cast<const float4*>(Qp + hf*32 + 8*g);
      const float4 b = *reinterpret_cast<const float4*>(Qp + hf*32 + 8*g + 4);
      f16x8 q;
      q[0]=(_Float16)(a.x*SCL); q[1]=(_Float16)(a.y*SCL);
      q[2]=(_Float16)(a.z*SCL); q[3]=(_Float16)(a.w*SCL);
      q[4]=(_Float16)(b.x*SCL); q[5]=(_Float16)(b.y*SCL);
      q[6]=(_Float16)(b.z*SCL); q[7]=(_Float16)(b.w*SCL);
      qf[u][hf] = q;
    }
  }
  const float* Mp0 = M + (size_t)qrow[0]*kS;
  const float* Mp1 = M + (size_t)qrow[1]*kS;

  const f32x4 zero4 = {0.f, 0.f, 0.f, 0.f};
  f32x4 acc[2][4];
  #pragma unroll
  for (int u = 0; u < 2; ++u)
    #pragma unroll
    for (int t = 0; t < 4; ++t) acc[u][t] = zero4;

  float mrun[2] = {-1e30f, -1e30f};
  float lsum[2] = {0.f, 0.f};

  // ---- prologue: stage chunk 0 ----
  #pragma unroll
  for (int i = 0; i < 8; ++i) {
    const int s = i*8 + sr;
    const float4 kv = *reinterpret_cast<const float4*>(Kp + (size_t)s*kRowF + sc4*4);
    const float4 vv = *reinterpret_cast<const float4*>(Vp + (size_t)s*kRowF + sc4*4);
    f16x4 kw;
    kw[0]=(_Float16)kv.x; kw[1]=(_Float16)kv.y; kw[2]=(_Float16)kv.z; kw[3]=(_Float16)kv.w;
    *reinterpret_cast<f16x4*>(&Ks[0][s][sc4*4]) = kw;
    Vt[0][sc4*4+0][s] = (_Float16)vv.x;
    Vt[0][sc4*4+1][s] = (_Float16)vv.y;
    Vt[0][sc4*4+2][s] = (_Float16)vv.z;
    Vt[0][sc4*4+3][s] = (_Float16)vv.w;
  }
  __syncthreads();

  int cur = 0;
  for (int c = 0; c < NCH; ++c) {
    const int s0 = c * KVB;
    const bool pre = (c + 1 < NCH);

    // issue next-chunk K loads early
    float4 ka[8];
    if (pre) {
      #pragma unroll
      for (int i = 0; i < 8; ++i)
        ka[i] = *reinterpret_cast<const float4*>(Kp + (size_t)(s0+KVB + i*8+sr)*kRowF + sc4*4);
    }

    // ---- QK^T: K-frags read once, used by both q-subtiles ----
    float x[2][16];
    #pragma unroll
    for (int st = 0; st < 4; ++st) {
      const f16x8 kf0 = *reinterpret_cast<const f16x8*>(&Ks[cur][st*16+qc][8*g]);
      const f16x8 kf1 = *reinterpret_cast<const f16x8*>(&Ks[cur][st*16+qc][32+8*g]);
      const float4 lv  = *reinterpret_cast<const float4*>(Lp  + s0 + st*16 + 4*g);
      const float4 mv0 = *reinterpret_cast<const float4*>(Mp0 + s0 + st*16 + 4*g);
      const float4 mv1 = *reinterpret_cast<const float4*>(Mp1 + s0 + st*16 + 4*g);
      __builtin_amdgcn_s_setprio(1);
      f32x4 c0 = zero4, c1 = zero4;
      c0 = __builtin_amdgcn_mfma_f32_16x16x32_f16(kf0, qf[0][0], c0, 0, 0, 0);
      c0 = __builtin_amdgcn_mfma_f32_16x16x32_f16(kf1, qf[0][1], c0, 0, 0, 0);
      c1 = __builtin_amdgcn_mfma_f32_16x16x32_f16(kf0, qf[1][0], c1, 0, 0, 0);
      c1 = __builtin_amdgcn_mfma_f32_16x16x32_f16(kf1, qf[1][1], c1, 0, 0, 0);
      __builtin_amdgcn_s_setprio(0);
      x[0][st*4+0] = fmaf(mv0.x + lv.x, SCL, c0[0]);
      x[0][st*4+1] = fmaf(mv0.y + lv.y, SCL, c0[1]);
      x[0][st*4+2] = fmaf(mv0.z + lv.z, SCL, c0[2]);
      x[0][st*4+3] = fmaf(mv0.w + lv.w, SCL, c0[3]);
      x[1][st*4+0] = fmaf(mv1.x + lv.x, SCL, c1[0]);
      x[1][st*4+1] = fmaf(mv1.y + lv.y, SCL, c1[1]);
      x[1][st*4+2] = fmaf(mv1.z + lv.z, SCL, c1[2]);
      x[1][st*4+3] = fmaf(mv1.w + lv.w, SCL, c1[3]);
    }

    // write next K (other buffer), then issue next V loads
    if (pre) {
      #pragma unroll
      for (int i = 0; i < 8; ++i) {
        const int s = i*8 + sr;
        f16x4 kw;
        kw[0]=(_Float16)ka[i].x; kw[1]=(_Float16)ka[i].y;
        kw[2]=(_Float16)ka[i].z; kw[3]=(_Float16)ka[i].w;
        *reinterpret_cast<f16x4*>(&Ks[cur^1][s][sc4*4]) = kw;
      }
    }
    float4 va[8];
    if (pre) {
      #pragma unroll
      for (int i = 0; i < 8; ++i)
        va[i] = *reinterpret_cast<const float4*>(Vp + (size_t)(s0+KVB + i*8+sr)*kRowF + sc4*4);
    }

    // ---- online softmax (both subtiles), defer-max THR=8 (log2 domain) ----
    float tmax[2];
    #pragma unroll
    for (int u = 0; u < 2; ++u) {
      float t = x[u][0];
      #pragma unroll
      for (int i = 1; i < 16; ++i) t = fmaxf(t, x[u][i]);
      t = fmaxf(t, __shfl_xor(t, 16));
      t = fmaxf(t, __shfl_xor(t, 32));
      tmax[u] = t;
    }
    const int ok = (tmax[0] <= mrun[0] + 8.f) && (tmax[1] <= mrun[1] + 8.f);
    if (!__all(ok)) {
      #pragma unroll
      for (int u = 0; u < 2; ++u) {
        const float mnew = fmaxf(mrun[u], tmax[u]);
        const float r = __builtin_amdgcn_exp2f(mrun[u] - mnew);
        mrun[u] = mnew;
        lsum[u] *= r;
        #pragma unroll
        for (int t = 0; t < 4; ++t) acc[u][t] *= r;
      }
    }
    #pragma unroll
    for (int u = 0; u < 2; ++u) {
      float ts = 0.f;
      #pragma unroll
      for (int i = 0; i < 16; ++i) {
        x[u][i] = __builtin_amdgcn_exp2f(x[u][i] - mrun[u]);
        ts += x[u][i];
      }
      ts += __shfl_xor(ts, 16);
      ts += __shfl_xor(ts, 32);
      lsum[u] += ts;
    }

    // ---- PV: V-frags read once, used by both q-subtiles ----
    #pragma unroll
    for (int st = 0; st < 4; ++st) {
      f16x4 pb0, pb1;
      pb0[0]=(_Float16)x[0][st*4+0]; pb0[1]=(_Float16)x[0][st*4+1];
      pb0[2]=(_Float16)x[0][st*4+2]; pb0[3]=(_Float16)x[0][st*4+3];
      pb1[0]=(_Float16)x[1][st*4+0]; pb1[1]=(_Float16)x[1][st*4+1];
      pb1[2]=(_Float16)x[1][st*4+2]; pb1[3]=(_Float16)x[1][st*4+3];
      __builtin_amdgcn_s_setprio(1);
      #pragma unroll
      for (int t = 0; t < 4; ++t) {
        const f16x4 vf = *reinterpret_cast<const f16x4*>(&Vt[cur][16*t+qc][st*16+4*g]);
        acc[0][t] = __builtin_amdgcn_mfma_f32_16x16x16f16(vf, pb0, acc[0][t], 0, 0, 0);
        acc[1][t] = __builtin_amdgcn_mfma_f32_16x16x16f16(vf, pb1, acc[1][t], 0, 0, 0);
      }
      __builtin_amdgcn_s_setprio(0);
    }

    // write next V (transposed scatter, 4-way at LDV=68), single barrier
    if (pre) {
      #pragma unroll
      for (int i = 0; i < 8; ++i) {
        const int s = i*8 + sr;
        Vt[cur^1][sc4*4+0][s] = (_Float16)va[i].x;
        Vt[cur^1][sc4*4+1][s] = (_Float16)va[i].y;
        Vt[cur^1][sc4*4+2][s] = (_Float16)va[i].z;
        Vt[cur^1][sc4*4+3][s] = (_Float16)va[i].w;
      }
      __syncthreads();
      cur ^= 1;
    }
  }

  // ---- epilogue: normalize, vectorized stores ----
  #pragma unroll
  for (int u = 0; u < 2; ++u) {
    const float inv = 1.f / lsum[u];
    float* Op = O + ((size_t)((size_t)n*kL + qrow[u])*kH + h)*kD;
    #pragma unroll
    for (int t = 0; t < 4; ++t) {
      float4 o;
      o.x = acc[u][t][0] * inv;
      o.y = acc[u][t][1] * inv;
      o.z = acc[u][t][2] * inv;
      o.w = acc[u][t][3] * inv;
      *reinterpret_cast<float4*>(Op + t*16 + 4*g) = o;
    }
  }
}

extern "C" void kernel_launch(void* const* d_in, const int* in_sizes, int n_in,
                              void* d_out, int out_size, void* d_ws, size_t ws_size,
                              hipStream_t stream) {
  const float* Q   = (const float*)d_in[0];
  const float* K   = (const float*)d_in[1];
  const float* V   = (const float*)d_in[2];
  const float* M   = (const float*)d_in[3];
  const float* KLN = (const float*)d_in[4];
  float* O = (float*)d_out;

  dim3 grid(kN * kH * (kL / 64));   // 1024 blocks
  dim3 block(128);                  // 2 waves, 32 queries each
  attn_fwd_kernel<<<grid, block, 0, stream>>>(Q, K, V, M, KLN, O);
}

// Round 5
// 62.579 us; speedup vs baseline: 2.9865x; 1.0485x over previous
//
#include <hip/hip_runtime.h>

typedef _Float16 f16x8 __attribute__((ext_vector_type(8)));
typedef _Float16 f16x4 __attribute__((ext_vector_type(4)));
typedef __fp16   hf2   __attribute__((ext_vector_type(2)));
typedef float    f32x4 __attribute__((ext_vector_type(4)));

namespace {
constexpr int kN = 4, kL = 1024, kS = 1024, kH = 16, kE = 64, kD = 64;
constexpr int kRowF = kH * kE;   // 1024 floats: s-row stride of K and V
constexpr int KVB  = 64;         // keys per LDS chunk
constexpr int NCH  = kS / KVB;   // 16 chunks
constexpr float SCL = 0.125f * 1.44269504088896340736f;  // 1/sqrt(E)*log2(e)
}

__device__ __forceinline__ f16x4 pk4(float a, float b, float c, float d) {
  union { hf2 h2[2]; f16x4 v; } u;
  u.h2[0] = __builtin_amdgcn_cvt_pkrtz(a, b);
  u.h2[1] = __builtin_amdgcn_cvt_pkrtz(c, d);
  return u.v;
}

// Block = 2 waves x 32 queries of one (n,h). K/V chunks in LDS (f16, flat
// 64x64, XOR slot-swizzled so ALL staging writes and fragment reads are
// bank-conflict-free), double-buffered, one barrier per chunk.
// Swapped scores: S^T = K.Q^T via mfma_16x16x32_f16; C/D layout
// (col=lane&15=q, row=4g+r=s) == B-frag of 16x16x16 f16, so P^T feeds PV
// (O^T = V^T.P^T) straight from registers.
//
// K LDS:  idx = s*64 + (b64slot ^ ((s&7)<<1))*4   (b128 pairs stay adjacent)
// V LDS:  idx = d*64 + (squad ^ ((d&15)^(d>>2)))*4
__global__ __launch_bounds__(128, 2)
void attn_fwd_kernel(const float* __restrict__ Q, const float* __restrict__ K,
                     const float* __restrict__ V, const float* __restrict__ M,
                     const float* __restrict__ KLN, float* __restrict__ O)
{
  __shared__ _Float16 Ks[2][KVB * 64];
  __shared__ _Float16 Vt[2][kD * 64];

  const int tid  = threadIdx.x;
  const int lane = tid & 63;
  const int wave = tid >> 6;    // 0..1
  const int qc   = lane & 15;
  const int g    = lane >> 4;
  const int sr   = tid >> 4;    // staging row id 0..7
  const int sc4  = tid & 15;    // staging float4 column

  // XCD-aware swizzle (1024 % 8 == 0 -> bijective): all 16 q-blocks of an
  // (n,h) land on one XCD so K/V stay L2-resident there.
  const int swz = ((blockIdx.x & 7) << 7) | (blockIdx.x >> 3);
  const int nh = swz >> 4, qb = swz & 15;
  const int h = nh & (kH - 1), n = nh >> 4;

  const int qbase = qb*64 + wave*32;

  const float* Kp = K + ((size_t)n*kS*kH + h)*kE;
  const float* Vp = V + ((size_t)n*kS*kH + h)*kD;
  const float* Lp = KLN + (size_t)n*kS;

  // ---- hoisted Q B-fragments (pre-scaled by SCL) ----
  f16x8 qf[2][2];
  int qrow[2];
  #pragma unroll
  for (int u = 0; u < 2; ++u) {
    qrow[u] = qbase + u*16 + qc;
    const float* Qp = Q + ((size_t)((size_t)n*kL + qrow[u])*kH + h)*kE;
    #pragma unroll
    for (int hf = 0; hf < 2; ++hf) {
      const f32x4 a = *reinterpret_cast<const f32x4*>(Qp + hf*32 + 8*g);
      const f32x4 b = *reinterpret_cast<const f32x4*>(Qp + hf*32 + 8*g + 4);
      f16x8 q;
      q[0]=(_Float16)(a[0]*SCL); q[1]=(_Float16)(a[1]*SCL);
      q[2]=(_Float16)(a[2]*SCL); q[3]=(_Float16)(a[3]*SCL);
      q[4]=(_Float16)(b[0]*SCL); q[5]=(_Float16)(b[1]*SCL);
      q[6]=(_Float16)(b[2]*SCL); q[7]=(_Float16)(b[3]*SCL);
      qf[u][hf] = q;
    }
  }
  const float* Mp0 = M + (size_t)qrow[0]*kS;
  const float* Mp1 = M + (size_t)qrow[1]*kS;

  // ---- per-thread LDS index constants ----
  // K frag read (f16 idx): row=st*16+qc, b128 slot (g+4hf)^(qc&7)
  const int koff = qc*64 + ((g ^ (qc & 7)) << 3);      // + st*1024, ^32 for hf=1
  // V frag read: row d=16t+qc, squad slot (4st+g)^hv[t]
  int hv[4], vrow[4];
  #pragma unroll
  for (int t = 0; t < 4; ++t) {
    hv[t] = (qc ^ (4*t + (qc >> 2))) & 15;
    vrow[t] = (16*t + qc) * 64;
  }
  // V write: d=4sc4+jd, slot=(sr+8qd)^hw[jd]
  int hw[4];
  #pragma unroll
  for (int jd = 0; jd < 4; ++jd)
    hw[jd] = ((4*(sc4 & 3) + jd) ^ sc4) & 15;

  const f32x4 zero4 = {0.f, 0.f, 0.f, 0.f};
  f32x4 acc[2][4];
  #pragma unroll
  for (int u = 0; u < 2; ++u)
    #pragma unroll
    for (int t = 0; t < 4; ++t) acc[u][t] = zero4;

  float mrun[2] = {-1e30f, -1e30f};
  float lsum[2] = {0.f, 0.f};

  // ---- staging helpers ----
  auto k_write = [&](int buf, const f32x4* ka) {
    #pragma unroll
    for (int i = 0; i < 8; ++i) {
      const int s = i*8 + sr;
      *reinterpret_cast<f16x4*>(&Ks[buf][s*64 + ((sc4 ^ ((s & 7) << 1)) << 2)]) =
          pk4(ka[i][0], ka[i][1], ka[i][2], ka[i][3]);
    }
  };
  auto v_write = [&](int buf, const f32x4* va) {
    #pragma unroll
    for (int qd = 0; qd < 2; ++qd)
      #pragma unroll
      for (int jd = 0; jd < 4; ++jd) {
        const int d = 4*sc4 + jd;
        const int slot = (sr + 8*qd) ^ hw[jd];
        *reinterpret_cast<f16x4*>(&Vt[buf][d*64 + slot*4]) =
            pk4(va[qd*4+0][jd], va[qd*4+1][jd], va[qd*4+2][jd], va[qd*4+3][jd]);
      }
  };

  // ---- prologue: stage chunk 0 into buffer 0 ----
  {
    f32x4 ka[8], va[8];
    #pragma unroll
    for (int i = 0; i < 8; ++i)
      ka[i] = *reinterpret_cast<const f32x4*>(Kp + (size_t)(i*8 + sr)*kRowF + sc4*4);
    #pragma unroll
    for (int qd = 0; qd < 2; ++qd)
      #pragma unroll
      for (int js = 0; js < 4; ++js)
        va[qd*4+js] = *reinterpret_cast<const f32x4*>(Vp + (size_t)(4*(sr+8*qd) + js)*kRowF + sc4*4);
    k_write(0, ka);
    v_write(0, va);
  }
  __syncthreads();

  int cur = 0;
  for (int c = 0; c < NCH; ++c) {
    const int s0 = c * KVB;
    const bool pre = (c + 1 < NCH);

    // issue next-chunk K loads early
    f32x4 ka[8];
    if (pre) {
      #pragma unroll
      for (int i = 0; i < 8; ++i)
        ka[i] = *reinterpret_cast<const f32x4*>(Kp + (size_t)(s0+KVB + i*8+sr)*kRowF + sc4*4);
    }

    // ---- QK^T: K-frags read once, used by both q-subtiles ----
    float x[2][16];
    #pragma unroll
    for (int st = 0; st < 4; ++st) {
      const f16x8 kf0 = *reinterpret_cast<const f16x8*>(&Ks[cur][st*1024 + koff]);
      const f16x8 kf1 = *reinterpret_cast<const f16x8*>(&Ks[cur][st*1024 + (koff ^ 32)]);
      const f32x4 lv  = *reinterpret_cast<const f32x4*>(Lp  + s0 + st*16 + 4*g);
      const f32x4 mv0 = *reinterpret_cast<const f32x4*>(Mp0 + s0 + st*16 + 4*g);
      const f32x4 mv1 = *reinterpret_cast<const f32x4*>(Mp1 + s0 + st*16 + 4*g);
      __builtin_amdgcn_s_setprio(1);
      f32x4 c0 = zero4, c1 = zero4;
      c0 = __builtin_amdgcn_mfma_f32_16x16x32_f16(kf0, qf[0][0], c0, 0, 0, 0);
      c0 = __builtin_amdgcn_mfma_f32_16x16x32_f16(kf1, qf[0][1], c0, 0, 0, 0);
      c1 = __builtin_amdgcn_mfma_f32_16x16x32_f16(kf0, qf[1][0], c1, 0, 0, 0);
      c1 = __builtin_amdgcn_mfma_f32_16x16x32_f16(kf1, qf[1][1], c1, 0, 0, 0);
      __builtin_amdgcn_s_setprio(0);
      #pragma unroll
      for (int r = 0; r < 4; ++r) {
        x[0][st*4+r] = fmaf(mv0[r] + lv[r], SCL, c0[r]);
        x[1][st*4+r] = fmaf(mv1[r] + lv[r], SCL, c1[r]);
      }
    }

    // write next K (other buffer), then issue next V loads
    if (pre) k_write(cur ^ 1, ka);
    f32x4 va[8];
    if (pre) {
      #pragma unroll
      for (int qd = 0; qd < 2; ++qd)
        #pragma unroll
        for (int js = 0; js < 4; ++js)
          va[qd*4+js] = *reinterpret_cast<const f32x4*>(Vp + (size_t)(s0+KVB + 4*(sr+8*qd)+js)*kRowF + sc4*4);
    }

    // ---- online softmax (both subtiles), defer-max THR=8 (log2 domain) ----
    float tmax[2];
    #pragma unroll
    for (int u = 0; u < 2; ++u) {
      float t = x[u][0];
      #pragma unroll
      for (int i = 1; i < 16; ++i) t = fmaxf(t, x[u][i]);
      t = fmaxf(t, __shfl_xor(t, 16));
      t = fmaxf(t, __shfl_xor(t, 32));
      tmax[u] = t;
    }
    const int ok = (tmax[0] <= mrun[0] + 8.f) && (tmax[1] <= mrun[1] + 8.f);
    if (!__all(ok)) {
      #pragma unroll
      for (int u = 0; u < 2; ++u) {
        const float mnew = fmaxf(mrun[u], tmax[u]);
        const float r = __builtin_amdgcn_exp2f(mrun[u] - mnew);
        mrun[u] = mnew;
        lsum[u] *= r;
        #pragma unroll
        for (int t = 0; t < 4; ++t) acc[u][t] *= r;
      }
    }
    #pragma unroll
    for (int u = 0; u < 2; ++u) {
      float ts = 0.f;
      #pragma unroll
      for (int i = 0; i < 16; ++i) {
        x[u][i] = __builtin_amdgcn_exp2f(x[u][i] - mrun[u]);
        ts += x[u][i];
      }
      ts += __shfl_xor(ts, 16);
      ts += __shfl_xor(ts, 32);
      lsum[u] += ts;
    }

    // ---- PV: V-frags read once (conflict-free b64), both q-subtiles ----
    #pragma unroll
    for (int st = 0; st < 4; ++st) {
      const f16x4 pb0 = pk4(x[0][st*4+0], x[0][st*4+1], x[0][st*4+2], x[0][st*4+3]);
      const f16x4 pb1 = pk4(x[1][st*4+0], x[1][st*4+1], x[1][st*4+2], x[1][st*4+3]);
      __builtin_amdgcn_s_setprio(1);
      #pragma unroll
      for (int t = 0; t < 4; ++t) {
        const int slot = ((4*st + g) ^ hv[t]) << 2;
        const f16x4 vf = *reinterpret_cast<const f16x4*>(&Vt[cur][vrow[t] + slot]);
        acc[0][t] = __builtin_amdgcn_mfma_f32_16x16x16f16(vf, pb0, acc[0][t], 0, 0, 0);
        acc[1][t] = __builtin_amdgcn_mfma_f32_16x16x16f16(vf, pb1, acc[1][t], 0, 0, 0);
      }
      __builtin_amdgcn_s_setprio(0);
    }

    // write next V (transposed in-registers, conflict-free b64), one barrier
    if (pre) {
      v_write(cur ^ 1, va);
      __syncthreads();
      cur ^= 1;
    }
  }

  // ---- epilogue: normalize, vectorized stores ----
  #pragma unroll
  for (int u = 0; u < 2; ++u) {
    const float inv = 1.f / lsum[u];
    float* Op = O + ((size_t)((size_t)n*kL + qrow[u])*kH + h)*kD;
    #pragma unroll
    for (int t = 0; t < 4; ++t) {
      f32x4 o;
      o[0] = acc[u][t][0] * inv;
      o[1] = acc[u][t][1] * inv;
      o[2] = acc[u][t][2] * inv;
      o[3] = acc[u][t][3] * inv;
      *reinterpret_cast<f32x4*>(Op + t*16 + 4*g) = o;
    }
  }
}

extern "C" void kernel_launch(void* const* d_in, const int* in_sizes, int n_in,
                              void* d_out, int out_size, void* d_ws, size_t ws_size,
                              hipStream_t stream) {
  const float* Q   = (const float*)d_in[0];
  const float* K   = (const float*)d_in[1];
  const float* V   = (const float*)d_in[2];
  const float* M   = (const float*)d_in[3];
  const float* KLN = (const float*)d_in[4];
  float* O = (float*)d_out;

  dim3 grid(kN * kH * (kL / 64));   // 1024 blocks
  dim3 block(128);                  // 2 waves, 32 queries each
  attn_fwd_kernel<<<grid, block, 0, stream>>>(Q, K, V, M, KLN, O);
}

// Round 6
// 59.895 us; speedup vs baseline: 3.1203x; 1.0448x over previous
//
#include <hip/hip_runtime.h>

typedef _Float16 f16x8  __attribute__((ext_vector_type(8)));
typedef _Float16 f16x4  __attribute__((ext_vector_type(4)));
typedef __fp16   hf2    __attribute__((ext_vector_type(2)));
typedef float    f32x4  __attribute__((ext_vector_type(4)));
typedef float    f32x16 __attribute__((ext_vector_type(16)));

namespace {
constexpr int kN = 4, kL = 1024, kS = 1024, kH = 16, kE = 64, kD = 64;
constexpr int kRowF = kH * kE;     // 1024 floats: s-row stride of K and V
constexpr int KVB = 64, NCH = kS / KVB;
constexpr float SCL = 0.125f * 1.44269504088896340736f;  // 1/sqrt(E)*log2(e)
}

__device__ __forceinline__ unsigned pku(float a, float b) {
  union { hf2 h; unsigned u; } u;
  u.h = __builtin_amdgcn_cvt_pkrtz(a, b);
  return u.u;
}
__device__ __forceinline__ f16x4 pk4(float a, float b, float c, float d) {
  union { hf2 h2[2]; f16x4 v; } u;
  u.h2[0] = __builtin_amdgcn_cvt_pkrtz(a, b);
  u.h2[1] = __builtin_amdgcn_cvt_pkrtz(c, d);
  return u.v;
}

// Block = 4 waves x 32 q of one (n,h); K/V chunks (KVB=64) in LDS f16,
// double-buffered, all accesses conflict-free via XOR slot swizzles.
// 32x32x16 MFMA throughout. Swapped scores: S^T = K.Q^T; C/D layout
// col=lane&31=q, row=(reg&3)+8*(reg>>2)+4*(lane>>5)=s. P redistributed to
// the PV B-frag (k=8*hi+j) via cvt_pkrtz + permlane32_swap (T12).
// T14: LDS writes of chunk c+1 at TOP of body c (loads issued in body c-1).
//
// K LDS: f16 idx = s*64 + ((squad ^ ((s&7)<<1))<<2)   (b128 pairs adjacent)
// V LDS: f16 idx = d*64 + ((squad ^ key(d))<<2), key(d)=((4*((d>>2)&3)+(d&3))^(d>>2))&15
__global__ __launch_bounds__(256, 2)
void attn_fwd_kernel(const float* __restrict__ Q, const float* __restrict__ K,
                     const float* __restrict__ V, const float* __restrict__ M,
                     const float* __restrict__ KLN, float* __restrict__ O)
{
  __shared__ _Float16 Ks[2][KVB * 64];
  __shared__ _Float16 Vt[2][kD * 64];

  const int tid  = threadIdx.x;
  const int lane = tid & 63;
  const int wave = tid >> 6;      // 0..3
  const int l31  = lane & 31;     // q within wave-tile; also s/d row in frags
  const int hi   = lane >> 5;
  const int sr   = tid >> 4;      // staging row id 0..15
  const int sc4  = tid & 15;      // staging float4 column

  // XCD swizzle (512 % 8 == 0 -> bijective); all 8 q-blocks of an (n,h)
  // land on one XCD.
  const int swz = ((blockIdx.x & 7) << 6) | (blockIdx.x >> 3);
  const int nh = swz >> 3, qb = swz & 7;
  const int h = nh & (kH - 1), n = nh >> 4;
  const int qrow = qb * 128 + wave * 32 + l31;

  const float* Kp = K + ((size_t)n * kS * kH + h) * kE;
  const float* Vp = V + ((size_t)n * kS * kH + h) * kD;
  const float* Lp = KLN + (size_t)n * kS;
  const float* Mp = M + (size_t)qrow * kS;

  // ---- hoisted Q B-frags (pre-scaled): qf[ec], k = 16*ec + 8*hi + j ----
  f16x8 qf[4];
  {
    const float* Qp = Q + ((size_t)((size_t)n * kL + qrow) * kH + h) * kE;
    #pragma unroll
    for (int ec = 0; ec < 4; ++ec) {
      const f32x4 a = *reinterpret_cast<const f32x4*>(Qp + 16*ec + 8*hi);
      const f32x4 b = *reinterpret_cast<const f32x4*>(Qp + 16*ec + 8*hi + 4);
      union { f16x4 h4[2]; f16x8 v; } u;
      u.h4[0] = pk4(a[0]*SCL, a[1]*SCL, a[2]*SCL, a[3]*SCL);
      u.h4[1] = pk4(b[0]*SCL, b[1]*SCL, b[2]*SCL, b[3]*SCL);
      qf[ec] = u.v;
    }
  }

  // ---- per-thread LDS constants ----
  const int kxor = (l31 & 7) << 1;          // K read swizzle key (even)
  int keyv[2], vrowb[2];
  #pragma unroll
  for (int dt = 0; dt < 2; ++dt) {
    const int d = 32*dt + l31;
    keyv[dt] = ((4*((d>>2)&3) + (d&3)) ^ (d>>2)) & 15;
    vrowb[dt] = d * 64;
  }
  int hwv[4];
  #pragma unroll
  for (int jd = 0; jd < 4; ++jd)
    hwv[jd] = ((4*(sc4 & 3) + jd) ^ sc4) & 15;

  const f32x16 z16 = {0,0,0,0, 0,0,0,0, 0,0,0,0, 0,0,0,0};
  f32x16 acc[2] = {z16, z16};
  float mrun = -1e30f, lsum = 0.f;

  // ---- staging helpers ----
  f32x4 ka[4], va[4];
  auto load_kv = [&](int sbase) {
    #pragma unroll
    for (int i = 0; i < 4; ++i)
      ka[i] = *reinterpret_cast<const f32x4*>(Kp + (size_t)(sbase + 16*i + sr) * kRowF + 4*sc4);
    #pragma unroll
    for (int js = 0; js < 4; ++js)
      va[js] = *reinterpret_cast<const f32x4*>(Vp + (size_t)(sbase + 4*sr + js) * kRowF + 4*sc4);
  };
  auto kv_write = [&](int buf) {
    #pragma unroll
    for (int i = 0; i < 4; ++i) {
      const int s = 16*i + sr;
      *reinterpret_cast<f16x4*>(&Ks[buf][s*64 + ((sc4 ^ ((s & 7) << 1)) << 2)]) =
          pk4(ka[i][0], ka[i][1], ka[i][2], ka[i][3]);
    }
    #pragma unroll
    for (int jd = 0; jd < 4; ++jd) {
      const int d = 4*sc4 + jd;
      *reinterpret_cast<f16x4*>(&Vt[buf][d*64 + ((sr ^ hwv[jd]) << 2)]) =
          pk4(va[0][jd], va[1][jd], va[2][jd], va[3][jd]);
    }
  };

  // ---- prologue ----
  load_kv(0);
  kv_write(0);
  load_kv(KVB);       // chunk 1 in flight; written at top of body 0

  for (int c = 0; c < NCH; ++c) {
    const int cur = c & 1;
    const int s0 = c * KVB;
    __syncthreads();
    if (c + 1 < NCH) kv_write(cur ^ 1);          // chunk c+1 (loaded in body c-1)
    if (c + 2 < NCH) load_kv((c + 2) * KVB);     // consumed at top of body c+1

    // mask / key_lengths prefetch (cover under QK)
    f32x4 mv[2][4], lv[2][4];
    #pragma unroll
    for (int st = 0; st < 2; ++st)
      #pragma unroll
      for (int m = 0; m < 4; ++m) {
        mv[st][m] = *reinterpret_cast<const f32x4*>(Mp + s0 + 32*st + 8*m + 4*hi);
        lv[st][m] = *reinterpret_cast<const f32x4*>(Lp + s0 + 32*st + 8*m + 4*hi);
      }

    // ---- QK^T: 2 s-tiles x 4 e-chunks of 32x32x16 ----
    f32x16 xc[2];
    #pragma unroll
    for (int st = 0; st < 2; ++st) {
      f32x16 cc = z16;
      __builtin_amdgcn_s_setprio(1);
      #pragma unroll
      for (int ec = 0; ec < 4; ++ec) {
        const f16x8 kf = *reinterpret_cast<const f16x8*>(
            &Ks[cur][l31*64 + st*2048 + ((((ec << 2) + (hi << 1)) ^ kxor) << 2)]);
        cc = __builtin_amdgcn_mfma_f32_32x32x16_f16(kf, qf[ec], cc, 0, 0, 0);
      }
      __builtin_amdgcn_s_setprio(0);
      xc[st] = cc;
    }

    // ---- logits ----
    float x[2][16];
    #pragma unroll
    for (int st = 0; st < 2; ++st)
      #pragma unroll
      for (int r = 0; r < 16; ++r)
        x[st][r] = fmaf(mv[st][r>>2][r&3] + lv[st][r>>2][r&3], SCL, xc[st][r]);

    // ---- online softmax: 31 in-lane fmax + ONE xor32 shuffle ----
    float tmax = x[0][0];
    #pragma unroll
    for (int i = 1; i < 16; ++i) tmax = fmaxf(tmax, x[0][i]);
    #pragma unroll
    for (int i = 0; i < 16; ++i) tmax = fmaxf(tmax, x[1][i]);
    tmax = fmaxf(tmax, __shfl_xor(tmax, 32));

    if (!__all(tmax <= mrun + 8.f)) {            // defer-max THR=8 (log2)
      const float mnew = fmaxf(mrun, tmax);
      const float rs = __builtin_amdgcn_exp2f(mrun - mnew);
      mrun = mnew; lsum *= rs;
      acc[0] *= rs; acc[1] *= rs;
    }
    float ps = 0.f;
    #pragma unroll
    for (int st = 0; st < 2; ++st)
      #pragma unroll
      for (int i = 0; i < 16; ++i) {
        x[st][i] = __builtin_amdgcn_exp2f(x[st][i] - mrun);
        ps += x[st][i];
      }
    lsum += ps;                                   // cross-lane sum deferred

    // ---- P -> PV B-frags via cvt_pk + permlane32_swap (T12) ----
    f16x8 pf[4];
    #pragma unroll
    for (int sc = 0; sc < 4; ++sc) {
      const int st = sc >> 1, b = (sc & 1) * 8;
      const unsigned k0 = pku(x[st][b+0], x[st][b+1]);
      const unsigned k1 = pku(x[st][b+2], x[st][b+3]);
      const unsigned s0_ = pku(x[st][b+4], x[st][b+5]);
      const unsigned s1_ = pku(x[st][b+6], x[st][b+7]);
      auto X = __builtin_amdgcn_permlane32_swap(k0, s0_, false, false);
      auto Y = __builtin_amdgcn_permlane32_swap(k1, s1_, false, false);
      union { unsigned u[4]; f16x8 v; } pu;
      pu.u[0] = X[0]; pu.u[1] = Y[0]; pu.u[2] = X[1]; pu.u[3] = Y[1];
      pf[sc] = pu.v;
    }

    // ---- PV: 2 d-tiles x 4 k-chunks of 32x32x16 ----
    #pragma unroll
    for (int dt = 0; dt < 2; ++dt) {
      __builtin_amdgcn_s_setprio(1);
      #pragma unroll
      for (int sc = 0; sc < 4; ++sc) {
        const int sl0 = ((sc << 2) + (hi << 1)) ^ keyv[dt];
        union { f16x4 h4[2]; f16x8 v; } vu;
        vu.h4[0] = *reinterpret_cast<const f16x4*>(&Vt[cur][vrowb[dt] + (sl0 << 2)]);
        vu.h4[1] = *reinterpret_cast<const f16x4*>(&Vt[cur][vrowb[dt] + ((sl0 ^ 1) << 2)]);
        acc[dt] = __builtin_amdgcn_mfma_f32_32x32x16_f16(vu.v, pf[sc], acc[dt], 0, 0, 0);
      }
      __builtin_amdgcn_s_setprio(0);
    }
  }

  // ---- epilogue ----
  lsum += __shfl_xor(lsum, 32);
  const float inv = 1.f / lsum;
  float* Op = O + ((size_t)((size_t)n * kL + qrow) * kH + h) * kD;
  #pragma unroll
  for (int dt = 0; dt < 2; ++dt)
    #pragma unroll
    for (int m = 0; m < 4; ++m) {
      f32x4 o;
      o[0] = acc[dt][4*m+0] * inv;
      o[1] = acc[dt][4*m+1] * inv;
      o[2] = acc[dt][4*m+2] * inv;
      o[3] = acc[dt][4*m+3] * inv;
      *reinterpret_cast<f32x4*>(Op + 32*dt + 8*m + 4*hi) = o;
    }
}

extern "C" void kernel_launch(void* const* d_in, const int* in_sizes, int n_in,
                              void* d_out, int out_size, void* d_ws, size_t ws_size,
                              hipStream_t stream) {
  const float* Q   = (const float*)d_in[0];
  const float* K   = (const float*)d_in[1];
  const float* V   = (const float*)d_in[2];
  const float* M   = (const float*)d_in[3];
  const float* KLN = (const float*)d_in[4];
  float* O = (float*)d_out;

  dim3 grid(kN * kH * (kL / 128));  // 512 blocks
  dim3 block(256);                  // 4 waves, 32 queries each
  attn_fwd_kernel<<<grid, block, 0, stream>>>(Q, K, V, M, KLN, O);
}